// Round 1
// baseline (585.042 us; speedup 1.0000x reference)
//
#include <hip/hip_runtime.h>
#include <hip/hip_bf16.h>

// Problem: N=131072, D=128, W=16, R=5
//   logit[n,r] = e1[n]^T C_r e2[n],  C_r = sum_w weight[w,r] * M_w
//   out[0] = loss = -mean(log_softmax(logit)[n, rels[n]])
//   out[1..N] = preds[n] = sum_r (r+1) * softmax(logit[n])[r]

#define NTOT 131072
#define DDIM 128
#define WBAS 16
#define RCLS 5
#define BN   64      // n-rows per block
#define TK   16      // C k-chunk rows
#define LDSP 132     // padded LDS stride (floats)

// ---- prep: C[r][d][e] = sum_w weight[w][r] * rel_embeds[w][d*128+e]; zero loss ----
__global__ __launch_bounds__(256) void prep_kernel(
    const float* __restrict__ rel_embeds,   // [W, D*D]
    const float* __restrict__ wsc,          // [W, R]
    float* __restrict__ C,                  // [R, D*D] out (workspace)
    float* __restrict__ out)                // d_out (zero loss slot)
{
    int idx = blockIdx.x * 256 + threadIdx.x;   // 0 .. R*D*D-1 (81920)
    if (idx == 0) out[0] = 0.0f;
    if (idx < RCLS * DDIM * DDIM) {
        int r  = idx / (DDIM * DDIM);
        int de = idx - r * (DDIM * DDIM);
        float acc = 0.0f;
#pragma unroll
        for (int w = 0; w < WBAS; ++w)
            acc += wsc[w * RCLS + r] * rel_embeds[w * (DDIM * DDIM) + de];
        C[idx] = acc;
    }
}

// ---- main fused kernel ----
__global__ __launch_bounds__(256) void bilinear_fused_kernel(
    const float* __restrict__ e1g,     // [N, D]
    const float* __restrict__ e2g,     // [N, D]
    const float* __restrict__ C,       // [R, D, D]
    const int*   __restrict__ rels,    // [N]
    float* __restrict__ out,           // [1 + N]
    float inv_n)
{
    __shared__ float s_e1[BN][LDSP];
    __shared__ float s_e2[BN][LDSP];
    __shared__ float s_c[TK][LDSP];
    __shared__ float s_logits[BN][RCLS];

    const int tid = threadIdx.x;
    const int nb  = blockIdx.x * BN;

    // stage e1/e2 tiles: 64 rows x 32 float4 each = 2048 f4 per tensor
#pragma unroll
    for (int i = 0; i < 8; ++i) {
        int idx = i * 256 + tid;          // float4 index
        int row = idx >> 5;
        int c4  = idx & 31;
        float4 v1 = ((const float4*)(e1g + (size_t)(nb + row) * DDIM))[c4];
        float4 v2 = ((const float4*)(e2g + (size_t)(nb + row) * DDIM))[c4];
        *(float4*)&s_e1[row][c4 * 4] = v1;
        *(float4*)&s_e2[row][c4 * 4] = v2;
    }

    const int ty = tid >> 4;      // 0..15
    const int tx = tid & 15;      // 0..15
    const int r0 = ty * 4;        // 4 rows per thread
    const int c0 = tx * 8;        // 8 cols per thread

#pragma unroll
    for (int r = 0; r < RCLS; ++r) {
        float acc[4][8];
#pragma unroll
        for (int i = 0; i < 4; ++i)
#pragma unroll
            for (int j = 0; j < 8; ++j) acc[i][j] = 0.0f;

        for (int d0 = 0; d0 < DDIM; d0 += TK) {
            __syncthreads();    // protect s_c (also covers initial e1/e2 stage)
            // stage C chunk: rows d0..d0+TK-1 of C_r  (TK*32 = 512 f4)
#pragma unroll
            for (int i = 0; i < 2; ++i) {
                int idx = i * 256 + tid;
                int row = idx >> 5;
                int c4  = idx & 31;
                float4 v = ((const float4*)(C + r * (DDIM * DDIM) + (d0 + row) * DDIM))[c4];
                *(float4*)&s_c[row][c4 * 4] = v;
            }
            __syncthreads();

#pragma unroll
            for (int kk = 0; kk < TK; ++kk) {
                float a[4];
#pragma unroll
                for (int i = 0; i < 4; ++i) a[i] = s_e1[r0 + i][d0 + kk];
                float4 b0 = *(const float4*)&s_c[kk][c0];
                float4 b1 = *(const float4*)&s_c[kk][c0 + 4];
                float b[8] = {b0.x, b0.y, b0.z, b0.w, b1.x, b1.y, b1.z, b1.w};
#pragma unroll
                for (int i = 0; i < 4; ++i)
#pragma unroll
                    for (int j = 0; j < 8; ++j)
                        acc[i][j] += a[i] * b[j];
            }
        }

        // contract with e2: logit[row, r] = sum_col T[row,col] * e2[row,col]
        float part[4];
#pragma unroll
        for (int i = 0; i < 4; ++i) {
            float4 v0 = *(const float4*)&s_e2[r0 + i][c0];
            float4 v1 = *(const float4*)&s_e2[r0 + i][c0 + 4];
            float e[8] = {v0.x, v0.y, v0.z, v0.w, v1.x, v1.y, v1.z, v1.w};
            float p = 0.0f;
#pragma unroll
            for (int j = 0; j < 8; ++j) p += acc[i][j] * e[j];
            part[i] = p;
        }
        // reduce across the 16 tx lanes (lane bits 0..3)
#pragma unroll
        for (int m = 1; m <= 8; m <<= 1)
#pragma unroll
            for (int i = 0; i < 4; ++i) part[i] += __shfl_xor(part[i], m);
        if (tx == 0) {
#pragma unroll
            for (int i = 0; i < 4; ++i) s_logits[r0 + i][r] = part[i];
        }
    }

    __syncthreads();

    // epilogue: one thread per row (tid < 64, all in wave 0)
    if (tid < BN) {
        float l[RCLS];
#pragma unroll
        for (int r = 0; r < RCLS; ++r) l[r] = s_logits[tid][r];
        float mx = l[0];
#pragma unroll
        for (int r = 1; r < RCLS; ++r) mx = fmaxf(mx, l[r]);
        float e[RCLS];
        float se = 0.0f;
#pragma unroll
        for (int r = 0; r < RCLS; ++r) { e[r] = expf(l[r] - mx); se += e[r]; }
        float inv_se = 1.0f / se;
        float pred = 0.0f;
#pragma unroll
        for (int r = 0; r < RCLS; ++r) pred += (float)(r + 1) * e[r] * inv_se;
        out[1 + nb + tid] = pred;

        int rel = rels[nb + tid];
        float lse = logf(se);
        float lp  = l[rel] - mx - lse;     // log_softmax at true class
        float lossc = -lp * inv_n;
        // full wave-64 reduce (tid 0..63 == wave 0)
#pragma unroll
        for (int m = 1; m <= 32; m <<= 1) lossc += __shfl_xor(lossc, m);
        if (tid == 0) atomicAdd(out, lossc);
    }
}

extern "C" void kernel_launch(void* const* d_in, const int* in_sizes, int n_in,
                              void* d_out, int out_size, void* d_ws, size_t ws_size,
                              hipStream_t stream) {
    const float* e1   = (const float*)d_in[0];   // [N, D]
    const float* e2   = (const float*)d_in[1];   // [N, D]
    const float* rele = (const float*)d_in[2];   // [W, D*D]
    const float* wsc  = (const float*)d_in[3];   // [W, R]
    const int*   rels = (const int*)d_in[4];     // [N]
    float* out = (float*)d_out;                  // [1 + N]
    float* C   = (float*)d_ws;                   // [R, D, D] = 327,680 B

    // prep: 81920 elements / 256 = 320 blocks
    prep_kernel<<<320, 256, 0, stream>>>(rele, wsc, C, out);

    // main: N / BN = 2048 blocks
    bilinear_fused_kernel<<<NTOT / BN, 256, 0, stream>>>(
        e1, e2, C, rels, out, 1.0f / (float)NTOT);
}

// Round 2
// 429.278 us; speedup vs baseline: 1.3629x; 1.3629x over previous
//
#include <hip/hip_runtime.h>
#include <stdint.h>

// Problem: N=131072, D=128, W=16, R=5
//   logit[n,r] = e1[n]^T C_r e2[n],  C_r = sum_w weight[w,r] * M_w
//   out[0] = -mean(log_softmax(logit)[n, rels[n]]),  out[1..N] = expected rating
//
// Strategy: fold W->R first (prep), then per-r GEMM T = e1 @ Ct_r^T on MFMA
// with 3-term bf16 hi/lo split (hi*hi + hi*lo + lo*hi, rel err ~2^-16),
// contract with fp32 e2 held in registers in C-fragment layout.

#define NTOT 131072
#define DDIM 128
#define WBAS 16
#define RCLS 5
#define BN   128     // n-rows per block -> 1024 blocks
#define SA   136     // LDS row stride in bf16 elems (272 B = 17*16: aligned, 2-way banks)

typedef __attribute__((ext_vector_type(8))) short bf16x8;
typedef __attribute__((ext_vector_type(4))) float f32x4;

__device__ __forceinline__ unsigned short f2bf(float x) {
    union { float f; unsigned u; } v; v.f = x;
    unsigned u = v.u + 0x7FFFu + ((v.u >> 16) & 1u);   // round-to-nearest-even
    return (unsigned short)(u >> 16);
}
__device__ __forceinline__ float bf2f(unsigned short h) {
    union { float f; unsigned u; } v; v.u = ((unsigned)h) << 16;
    return v.f;
}

// ---- prep: Ct[r][e][d] = bf16_hi/lo( sum_w wsc[w][r] * rel[w][d*128+e] ); zero loss ----
__global__ __launch_bounds__(256) void prep_kernel(
    const float* __restrict__ rel_embeds,    // [W, D*D] (d-major: [d][e])
    const float* __restrict__ wsc,           // [W, R]
    unsigned short* __restrict__ Cth,        // [R, D, D] bf16 hi, [e][d] layout
    unsigned short* __restrict__ Ctl,        // [R, D, D] bf16 lo
    float* __restrict__ out)
{
    int idx = blockIdx.x * 256 + threadIdx.x;     // 0 .. 81919
    if (idx == 0) out[0] = 0.0f;
    if (idx < RCLS * DDIM * DDIM) {
        int r   = idx >> 14;
        int rem = idx & 16383;
        int e   = rem >> 7;
        int d   = rem & 127;
        float acc = 0.0f;
#pragma unroll
        for (int w = 0; w < WBAS; ++w)
            acc += wsc[w * RCLS + r] * rel_embeds[w * 16384 + d * 128 + e];
        unsigned short hi = f2bf(acc);
        Cth[idx] = hi;
        Ctl[idx] = f2bf(acc - bf2f(hi));
    }
}

// ---- main fused kernel: 256 threads = 4 waves; wave (wr,wc) owns 64x64 quadrant ----
__global__ __launch_bounds__(256, 2) void bilinear_mfma_kernel(
    const float* __restrict__ e1g,           // [N, D]
    const float* __restrict__ e2g,           // [N, D]
    const unsigned short* __restrict__ Cth,  // [R, 128, 128] bf16
    const unsigned short* __restrict__ Ctl,
    const int*   __restrict__ rels,          // [N]
    float* __restrict__ out,                 // [1 + N]
    float inv_n)
{
    __shared__ __align__(16) unsigned short s_hi[BN][SA];
    __shared__ __align__(16) unsigned short s_lo[BN][SA];
    __shared__ float s_logit[BN][RCLS];

    const int tid = threadIdx.x;
    const int n0  = blockIdx.x * BN;

    // zero logit accumulators
    for (int i = tid; i < BN * RCLS; i += 256) ((float*)s_logit)[i] = 0.0f;

    const int lane = tid & 63;
    const int wv   = tid >> 6;
    const int wr   = wv >> 1;       // row-band: rows [64*wr, 64*wr+64)
    const int wc   = wv & 1;        // col-band: cols [64*wc, 64*wc+64)
    const int l15  = lane & 15;
    const int q    = lane >> 4;     // quad id (k-chunk / C-row group)

    // preload e2 in C-fragment layout: e2r[mt][nt][i] = e2[n0+row][col]
    //   row = 64*wr + 16*mt + 4*q + i, col = 64*wc + 16*nt + l15
    float e2r[4][4][4];
#pragma unroll
    for (int mt = 0; mt < 4; ++mt)
#pragma unroll
        for (int i = 0; i < 4; ++i) {
            int row = 64 * wr + 16 * mt + 4 * q + i;
            const float* p = e2g + (size_t)(n0 + row) * DDIM + 64 * wc + l15;
#pragma unroll
            for (int nt = 0; nt < 4; ++nt) e2r[mt][nt][i] = p[16 * nt];
        }

    // stage e1 tile -> bf16 hi/lo in LDS (128 rows x 32 float4 = 4096 f4)
#pragma unroll
    for (int it = 0; it < 16; ++it) {
        int idx = it * 256 + tid;
        int row = idx >> 5, c4 = idx & 31;
        float4 v = ((const float4*)(e1g + (size_t)(n0 + row) * DDIM))[c4];
        unsigned short hx = f2bf(v.x), hy = f2bf(v.y), hz = f2bf(v.z), hw = f2bf(v.w);
        ushort4 hv = make_ushort4(hx, hy, hz, hw);
        ushort4 lv = make_ushort4(f2bf(v.x - bf2f(hx)), f2bf(v.y - bf2f(hy)),
                                  f2bf(v.z - bf2f(hz)), f2bf(v.w - bf2f(hw)));
        *(ushort4*)&s_hi[row][c4 * 4] = hv;
        *(ushort4*)&s_lo[row][c4 * 4] = lv;
    }
    __syncthreads();

    // per-lane B element offsets (bf16 elems): Ct[r][e][k], e = 64*wc+16*nt+l15
    int bofs[4];
#pragma unroll
    for (int nt = 0; nt < 4; ++nt)
        bofs[nt] = (64 * wc + 16 * nt + l15) * DDIM + q * 8;

#pragma unroll
    for (int r = 0; r < RCLS; ++r) {
        f32x4 acc[4][4];
#pragma unroll
        for (int mt = 0; mt < 4; ++mt)
#pragma unroll
            for (int nt = 0; nt < 4; ++nt) {
                f32x4 z = {0.0f, 0.0f, 0.0f, 0.0f};
                acc[mt][nt] = z;
            }

        const unsigned short* bh = Cth + r * 16384;
        const unsigned short* bl = Ctl + r * 16384;

        // K-extension: seg0 A=hi,B=hi | seg1 A=hi,B=lo | seg2 A=lo,B=hi
#pragma unroll
        for (int seg = 0; seg < 3; ++seg) {
            const unsigned short* bs = (seg == 1) ? bl : bh;
            const unsigned short (*sa)[SA] = (seg == 2) ? s_lo : s_hi;
#pragma unroll
            for (int k4 = 0; k4 < 4; ++k4) {
                bf16x8 a[4], b[4];
#pragma unroll
                for (int mt = 0; mt < 4; ++mt)
                    a[mt] = *(const bf16x8*)&sa[64 * wr + 16 * mt + l15][k4 * 32 + q * 8];
#pragma unroll
                for (int nt = 0; nt < 4; ++nt)
                    b[nt] = *(const bf16x8*)(bs + bofs[nt] + k4 * 32);
#pragma unroll
                for (int mt = 0; mt < 4; ++mt)
#pragma unroll
                    for (int nt = 0; nt < 4; ++nt)
                        acc[mt][nt] = __builtin_amdgcn_mfma_f32_16x16x32_bf16(
                            a[mt], b[nt], acc[mt][nt], 0, 0, 0);
            }
        }

        // contract with e2 (registers), reduce over 16 cols per tile, accumulate logits
#pragma unroll
        for (int mt = 0; mt < 4; ++mt)
#pragma unroll
            for (int i = 0; i < 4; ++i) {
                float p = acc[mt][0][i] * e2r[mt][0][i] + acc[mt][1][i] * e2r[mt][1][i]
                        + acc[mt][2][i] * e2r[mt][2][i] + acc[mt][3][i] * e2r[mt][3][i];
                p += __shfl_xor(p, 1);
                p += __shfl_xor(p, 2);
                p += __shfl_xor(p, 4);
                p += __shfl_xor(p, 8);
                if (l15 == 0)
                    atomicAdd(&s_logit[64 * wr + 16 * mt + 4 * q + i][r], p);
            }
    }
    __syncthreads();

    // epilogue: one thread per row (tid < 128 -> waves 0,1 fully active)
    if (tid < BN) {
        float l[RCLS];
#pragma unroll
        for (int r = 0; r < RCLS; ++r) l[r] = s_logit[tid][r];
        float mx = l[0];
#pragma unroll
        for (int r = 1; r < RCLS; ++r) mx = fmaxf(mx, l[r]);
        float e[RCLS], se = 0.0f;
#pragma unroll
        for (int r = 0; r < RCLS; ++r) { e[r] = __expf(l[r] - mx); se += e[r]; }
        float inv_se = 1.0f / se;
        float pred = 0.0f;
#pragma unroll
        for (int r = 0; r < RCLS; ++r) pred += (float)(r + 1) * e[r] * inv_se;
        out[1 + n0 + tid] = pred;

        int rel = rels[n0 + tid];
        float lossc = -(l[rel] - mx - logf(se)) * inv_n;
#pragma unroll
        for (int m = 1; m <= 32; m <<= 1) lossc += __shfl_xor(lossc, m);
        if (lane == 0) atomicAdd(out, lossc);
    }
}

extern "C" void kernel_launch(void* const* d_in, const int* in_sizes, int n_in,
                              void* d_out, int out_size, void* d_ws, size_t ws_size,
                              hipStream_t stream) {
    const float* e1   = (const float*)d_in[0];
    const float* e2   = (const float*)d_in[1];
    const float* rele = (const float*)d_in[2];
    const float* wsc  = (const float*)d_in[3];
    const int*   rels = (const int*)d_in[4];
    float* out = (float*)d_out;

    unsigned short* Cth = (unsigned short*)d_ws;             // 163840 B
    unsigned short* Ctl = Cth + RCLS * DDIM * DDIM;          // +163840 B

    prep_kernel<<<320, 256, 0, stream>>>(rele, wsc, Cth, Ctl, out);
    bilinear_mfma_kernel<<<NTOT / BN, 256, 0, stream>>>(
        e1, e2, Cth, Ctl, rels, out, 1.0f / (float)NTOT);
}

// Round 3
// 241.754 us; speedup vs baseline: 2.4200x; 1.7757x over previous
//
#include <hip/hip_runtime.h>
#include <stdint.h>

// Problem: N=131072, D=128, W=16, R=5
//   logit[n,r] = e1[n]^T C_r e2[n],  C_r = sum_w weight[w,r] * M_w
//   out[0] = -mean(log_softmax(logit)[n, rels[n]]),  out[1..N] = expected rating
//
// R3: BN=64, 4 waves, wave w = all 64 rows x cols [32w,32w+32).
// 3-term bf16 split (hi*hi + hi*lo + lo*hi) with fused per-k4 segment loop
// (a_hi reused for b_hi/b_lo; b_hi reused for a_hi/a_lo).
// e2 held in 32 regs in C-fragment layout; LDS = e1 hi/lo only (36 KB).

#define NTOT 131072
#define DDIM 128
#define WBAS 16
#define RCLS 5
#define BN   64
#define SA   136     // LDS row stride (bf16 elems); 272 B -> 2-way banks (free)

typedef __attribute__((ext_vector_type(8))) short bf16x8;
typedef __attribute__((ext_vector_type(4))) float f32x4;

__device__ __forceinline__ unsigned short f2bf(float x) {
    union { float f; unsigned u; } v; v.f = x;
    unsigned u = v.u + 0x7FFFu + ((v.u >> 16) & 1u);
    return (unsigned short)(u >> 16);
}
__device__ __forceinline__ float bf2f(unsigned short h) {
    union { float f; unsigned u; } v; v.u = ((unsigned)h) << 16;
    return v.f;
}

// ---- prep: Ct[r][e][d] = bf16 hi/lo of sum_w wsc[w][r]*rel[w][d*128+e]; zero loss ----
__global__ __launch_bounds__(256) void prep_kernel(
    const float* __restrict__ rel_embeds,    // [W, D*D]  ([d][e] inner)
    const float* __restrict__ wsc,           // [W, R]
    unsigned short* __restrict__ Cth,        // [R, 128, 128]  ([e][d] inner)
    unsigned short* __restrict__ Ctl,
    float* __restrict__ out)
{
    int idx = blockIdx.x * 256 + threadIdx.x;     // 0 .. 81919
    if (idx == 0) out[0] = 0.0f;
    if (idx < RCLS * DDIM * DDIM) {
        int r   = idx >> 14;
        int rem = idx & 16383;
        int e   = rem >> 7;
        int d   = rem & 127;
        float acc = 0.0f;
#pragma unroll
        for (int w = 0; w < WBAS; ++w)
            acc += wsc[w * RCLS + r] * rel_embeds[w * 16384 + d * 128 + e];
        unsigned short hi = f2bf(acc);
        Cth[idx] = hi;
        Ctl[idx] = f2bf(acc - bf2f(hi));
    }
}

// ---- main fused kernel ----
__global__ __launch_bounds__(256, 3) void bilinear_mfma_kernel(
    const float* __restrict__ e1g,           // [N, D]
    const float* __restrict__ e2g,           // [N, D]
    const unsigned short* __restrict__ Cth,  // [R, 128, 128] bf16 hi
    const unsigned short* __restrict__ Ctl,  // bf16 lo
    const int*   __restrict__ rels,
    float* __restrict__ out,                 // [1 + N]
    float inv_n)
{
    __shared__ __align__(16) unsigned short s_hi[BN][SA];
    __shared__ __align__(16) unsigned short s_lo[BN][SA];
    __shared__ float s_logit[BN][RCLS];

    const int tid = threadIdx.x;
    const int n0  = blockIdx.x * BN;

    for (int i = tid; i < BN * RCLS; i += 256) ((float*)s_logit)[i] = 0.0f;

    const int lane = tid & 63;
    const int w    = tid >> 6;      // wave id -> col band [32w, 32w+32)
    const int l15  = lane & 15;
    const int q    = lane >> 4;

    // e2 in C-fragment layout: e2r[mt][nt][i] = e2[n0 + 16mt+4q+i][32w + 16nt + l15]
    float e2r[4][2][4];
#pragma unroll
    for (int mt = 0; mt < 4; ++mt)
#pragma unroll
        for (int i = 0; i < 4; ++i) {
            const float* p = e2g + (size_t)(n0 + 16 * mt + 4 * q + i) * DDIM + 32 * w + l15;
            e2r[mt][0][i] = p[0];
            e2r[mt][1][i] = p[16];
        }

    // stage e1 -> bf16 hi/lo in LDS (64 rows x 32 float4)
#pragma unroll
    for (int it = 0; it < 8; ++it) {
        int idx = it * 256 + tid;
        int row = idx >> 5, c4 = idx & 31;
        float4 v = ((const float4*)(e1g + (size_t)(n0 + row) * DDIM))[c4];
        unsigned short hx = f2bf(v.x), hy = f2bf(v.y), hz = f2bf(v.z), hw = f2bf(v.w);
        *(ushort4*)&s_hi[row][c4 * 4] = make_ushort4(hx, hy, hz, hw);
        *(ushort4*)&s_lo[row][c4 * 4] = make_ushort4(
            f2bf(v.x - bf2f(hx)), f2bf(v.y - bf2f(hy)),
            f2bf(v.z - bf2f(hz)), f2bf(v.w - bf2f(hw)));
    }
    __syncthreads();

    const int bofs0 = (32 * w + l15) * DDIM + q * 8;        // nt=0
    const int bofs1 = (32 * w + 16 + l15) * DDIM + q * 8;   // nt=1

#pragma unroll
    for (int r = 0; r < RCLS; ++r) {
        f32x4 acc[4][2];
#pragma unroll
        for (int mt = 0; mt < 4; ++mt)
#pragma unroll
            for (int nt = 0; nt < 2; ++nt) {
                f32x4 z = {0.0f, 0.0f, 0.0f, 0.0f};
                acc[mt][nt] = z;
            }

        const unsigned short* bh = Cth + r * 16384;
        const unsigned short* bl = Ctl + r * 16384;

#pragma unroll
        for (int k4 = 0; k4 < 4; ++k4) {
            bf16x8 bhi[2], blo[2], ahi[4], alo[4];
            bhi[0] = *(const bf16x8*)(bh + bofs0 + k4 * 32);
            bhi[1] = *(const bf16x8*)(bh + bofs1 + k4 * 32);
            blo[0] = *(const bf16x8*)(bl + bofs0 + k4 * 32);
            blo[1] = *(const bf16x8*)(bl + bofs1 + k4 * 32);
#pragma unroll
            for (int mt = 0; mt < 4; ++mt) {
                ahi[mt] = *(const bf16x8*)&s_hi[16 * mt + l15][k4 * 32 + q * 8];
                alo[mt] = *(const bf16x8*)&s_lo[16 * mt + l15][k4 * 32 + q * 8];
            }
#pragma unroll
            for (int mt = 0; mt < 4; ++mt)
#pragma unroll
                for (int nt = 0; nt < 2; ++nt) {
                    acc[mt][nt] = __builtin_amdgcn_mfma_f32_16x16x32_bf16(
                        ahi[mt], bhi[nt], acc[mt][nt], 0, 0, 0);
                    acc[mt][nt] = __builtin_amdgcn_mfma_f32_16x16x32_bf16(
                        ahi[mt], blo[nt], acc[mt][nt], 0, 0, 0);
                    acc[mt][nt] = __builtin_amdgcn_mfma_f32_16x16x32_bf16(
                        alo[mt], bhi[nt], acc[mt][nt], 0, 0, 0);
                }
        }

        // contract with e2, reduce over the 16 l15 lanes, accumulate logits
#pragma unroll
        for (int mt = 0; mt < 4; ++mt)
#pragma unroll
            for (int i = 0; i < 4; ++i) {
                float p = acc[mt][0][i] * e2r[mt][0][i] + acc[mt][1][i] * e2r[mt][1][i];
                p += __shfl_xor(p, 1);
                p += __shfl_xor(p, 2);
                p += __shfl_xor(p, 4);
                p += __shfl_xor(p, 8);
                if (l15 == 0)
                    atomicAdd(&s_logit[16 * mt + 4 * q + i][r], p);
            }
    }
    __syncthreads();

    // epilogue: one thread per row
    if (tid < BN) {
        float l[RCLS];
#pragma unroll
        for (int r = 0; r < RCLS; ++r) l[r] = s_logit[tid][r];
        float mx = l[0];
#pragma unroll
        for (int r = 1; r < RCLS; ++r) mx = fmaxf(mx, l[r]);
        float e[RCLS], se = 0.0f;
#pragma unroll
        for (int r = 0; r < RCLS; ++r) { e[r] = __expf(l[r] - mx); se += e[r]; }
        float inv_se = 1.0f / se;
        float pred = 0.0f;
#pragma unroll
        for (int r = 0; r < RCLS; ++r) pred += (float)(r + 1) * e[r] * inv_se;
        out[1 + n0 + tid] = pred;

        int rel = rels[n0 + tid];
        float lossc = -(l[rel] - mx - logf(se)) * inv_n;
#pragma unroll
        for (int m = 1; m <= 32; m <<= 1) lossc += __shfl_xor(lossc, m);
        if (lane == 0) atomicAdd(out, lossc);
    }
}

extern "C" void kernel_launch(void* const* d_in, const int* in_sizes, int n_in,
                              void* d_out, int out_size, void* d_ws, size_t ws_size,
                              hipStream_t stream) {
    const float* e1   = (const float*)d_in[0];
    const float* e2   = (const float*)d_in[1];
    const float* rele = (const float*)d_in[2];
    const float* wsc  = (const float*)d_in[3];
    const int*   rels = (const int*)d_in[4];
    float* out = (float*)d_out;

    unsigned short* Cth = (unsigned short*)d_ws;             // 163840 B
    unsigned short* Ctl = Cth + RCLS * DDIM * DDIM;          // +163840 B

    prep_kernel<<<320, 256, 0, stream>>>(rele, wsc, Cth, Ctl, out);
    bilinear_mfma_kernel<<<NTOT / BN, 256, 0, stream>>>(
        e1, e2, Cth, Ctl, rels, out, 1.0f / (float)NTOT);
}